// Round 1
// baseline (21691.422 us; speedup 1.0000x reference)
//
#include <hip/hip_runtime.h>

// AGGCN (adaptive graph-conv GRU), fp32 correctness-first baseline.
// N=512 nodes, T=12 steps, B=64 batch, DIN=2, H=128, D=16, K=3 (Chebyshev), 2 layers.

constexpr int N_   = 512;
constexpr int T_   = 12;
constexpr int B_   = 64;
constexpr int DIN_ = 2;
constexpr int H_   = 128;
constexpr int D_   = 16;
constexpr int K_   = 3;

// ---------------------------------------------------------------------------
// LayerNorm over D=16 of (node_emb[n] + time_emb[t]) -> ne[(t*N+n)*D + d]
__global__ void ln_kernel(const float* __restrict__ nemb, const float* __restrict__ temb,
                          const float* __restrict__ g, const float* __restrict__ b,
                          float* __restrict__ ne) {
    int idx = blockIdx.x * 256 + threadIdx.x;
    if (idx >= T_ * N_) return;
    int t = idx / N_, n = idx % N_;
    float x[D_];
    float m = 0.f;
#pragma unroll
    for (int d = 0; d < D_; d++) { x[d] = nemb[n * D_ + d] + temb[t * D_ + d]; m += x[d]; }
    m *= (1.f / D_);
    float v = 0.f;
#pragma unroll
    for (int d = 0; d < D_; d++) { float c = x[d] - m; v += c * c; }
    v *= (1.f / D_);
    float rs = rsqrtf(v + 1e-12f);
#pragma unroll
    for (int d = 0; d < D_; d++) ne[(long)idx * D_ + d] = (x[d] - m) * rs * g[d] + b[d];
}

// ---------------------------------------------------------------------------
// S[t] = row-softmax(ne[t] @ ne[t]^T). One wave per row (8 cols/lane).
__global__ void support_softmax(const float* __restrict__ ne, float* __restrict__ S) {
    int rid = blockIdx.x;            // t*N + n
    int t = rid / N_, n = rid % N_;
    const float* net = ne + (long)t * N_ * D_;
    int lane = threadIdx.x;          // 64
    float r[D_];
#pragma unroll
    for (int d = 0; d < D_; d++) r[d] = net[(long)n * D_ + d];
    float v[8];
    float mx = -1e30f;
#pragma unroll
    for (int jj = 0; jj < 8; jj++) {
        const float* nj = net + (long)(jj * 64 + lane) * D_;
        float acc = 0.f;
#pragma unroll
        for (int d = 0; d < D_; d++) acc = fmaf(r[d], nj[d], acc);
        v[jj] = acc;
        mx = fmaxf(mx, acc);
    }
#pragma unroll
    for (int off = 32; off >= 1; off >>= 1) mx = fmaxf(mx, __shfl_xor(mx, off, 64));
    float s = 0.f;
#pragma unroll
    for (int jj = 0; jj < 8; jj++) { v[jj] = __expf(v[jj] - mx); s += v[jj]; }
#pragma unroll
    for (int off = 32; off >= 1; off >>= 1) s += __shfl_xor(s, off, 64);
    float inv = 1.f / s;
    float* Srow = S + (long)rid * N_;
#pragma unroll
    for (int jj = 0; jj < 8; jj++) Srow[jj * 64 + lane] = v[jj] * inv;
}

// ---------------------------------------------------------------------------
// Reorder W (D,K,cin,out) -> Wr (K,cin,out,D): makes d contiguous for pooling.
__global__ void reorder_W(const float* __restrict__ W, float* __restrict__ Wr,
                          int cin, int outdim) {
    int total = K_ * cin * outdim * D_;
    int idx = blockIdx.x * 256 + threadIdx.x;
    if (idx >= total) return;
    int d = idx & (D_ - 1);
    int rest = idx >> 4;            // (k*cin + i)*outdim + o
    int o = rest % outdim;
    int ki = rest / outdim;         // k*cin + i
    Wr[idx] = W[((long)d * K_ * cin + ki) * outdim + o];
}

// ---------------------------------------------------------------------------
// xg[k=0 slice][(n*B+b)*cin + c] = concat(xt, (z*)h) per node-major layout.
__global__ void build_xcat(float* __restrict__ xg, const float* __restrict__ xt,
                           long sb, long sn, int cx, int cin,
                           const float* __restrict__ h, const float* __restrict__ zr,
                           int use_z) {
    int n = blockIdx.y;
    int idx = blockIdx.x * 256 + threadIdx.x;
    if (idx >= B_ * cin) return;
    int b = idx / cin, c = idx - b * cin;
    float v;
    if (c < cx) {
        v = xt[(long)b * sb + (long)n * sn + c];
    } else {
        int q = c - cx;
        v = h[((long)n * B_ + b) * H_ + q];
        if (use_z) v *= zr[((long)n * B_ + b) * (2 * H_) + q];
    }
    xg[((long)n * B_ + b) * cin + c] = v;
}

// ---------------------------------------------------------------------------
// C(512 x F) = alpha * A(512x512) @ Bm(512xF)  [- Dsub if given]
// 128x128 tile, BK=16, 256 threads, 8x8 per thread.
__global__ __launch_bounds__(256) void gemm128(const float* __restrict__ A,
                                               const float* __restrict__ Bm,
                                               float* __restrict__ C,
                                               int Kd, int F, float alpha,
                                               const float* __restrict__ Dsub) {
    __shared__ float As[16][132];
    __shared__ float Bs[16][132];
    int tid = threadIdx.x;
    int bm = blockIdx.y * 128, bf = blockIdx.x * 128;
    int tr = tid >> 4, tc = tid & 15;
    float acc[8][8] = {};
    for (int k0 = 0; k0 < Kd; k0 += 16) {
#pragma unroll
        for (int p = 0; p < 2; p++) {
            int idx = tid + p * 256;
            int row = idx >> 2, kq = (idx & 3) << 2;
            const float4 v = *(const float4*)&A[(long)(bm + row) * Kd + k0 + kq];
            As[kq + 0][row] = v.x; As[kq + 1][row] = v.y;
            As[kq + 2][row] = v.z; As[kq + 3][row] = v.w;
        }
#pragma unroll
        for (int p = 0; p < 2; p++) {
            int idx = tid + p * 256;
            int kk = idx >> 5, fq = (idx & 31) << 2;
            *(float4*)&Bs[kk][fq] = *(const float4*)&Bm[(long)(k0 + kk) * F + bf + fq];
        }
        __syncthreads();
#pragma unroll
        for (int kk = 0; kk < 16; kk++) {
            float a[8], b[8];
            *(float4*)&a[0] = *(const float4*)&As[kk][tr * 8];
            *(float4*)&a[4] = *(const float4*)&As[kk][tr * 8 + 4];
            *(float4*)&b[0] = *(const float4*)&Bs[kk][tc * 8];
            *(float4*)&b[4] = *(const float4*)&Bs[kk][tc * 8 + 4];
#pragma unroll
            for (int i = 0; i < 8; i++)
#pragma unroll
                for (int j = 0; j < 8; j++) acc[i][j] = fmaf(a[i], b[j], acc[i][j]);
        }
        __syncthreads();
    }
#pragma unroll
    for (int i = 0; i < 8; i++) {
        int m = bm + tr * 8 + i;
#pragma unroll
        for (int j2 = 0; j2 < 2; j2++) {
            int f0 = bf + tc * 8 + j2 * 4;
            float4 v;
            v.x = alpha * acc[i][j2 * 4 + 0];
            v.y = alpha * acc[i][j2 * 4 + 1];
            v.z = alpha * acc[i][j2 * 4 + 2];
            v.w = alpha * acc[i][j2 * 4 + 3];
            if (Dsub) {
                const float4 dv = *(const float4*)&Dsub[(long)m * F + f0];
                v.x -= dv.x; v.y -= dv.y; v.z -= dv.z; v.w -= dv.w;
            }
            *(float4*)&C[(long)m * F + f0] = v;
        }
    }
}

// ---------------------------------------------------------------------------
// Fused per-node GEMM with on-the-fly weight pooling + GRU epilogues.
// out[n,b,o] = bias_n[o] + sum_{k,i} xg[k,n,b,i] * (sum_d ne[n,d] * W[d,k,i,o])
// mode 1: sigmoid -> dst (zr).  mode 2: tanh -> h' = r*h + (1-r)*hc; store h & dst.
__global__ __launch_bounds__(256) void node_gemm(const float* __restrict__ xg,
                                                 const float* __restrict__ ne_t,
                                                 const float* __restrict__ Wr,
                                                 const float* __restrict__ bpool,
                                                 int cin, int outdim, int mode,
                                                 const float* __restrict__ zr,
                                                 float* __restrict__ h,
                                                 float* __restrict__ dst,
                                                 long dn, long db) {
    __shared__ float xs[16][68];
    __shared__ float wsd[16][68];
    int n = blockIdx.y;
    int ob = blockIdx.x * 64;
    int tid = threadIdx.x;
    int tr = tid >> 4, tc = tid & 15;
    int ol = tid & 63, iq = tid >> 6;

    float nerow[D_];
#pragma unroll
    for (int d = 0; d < D_; d++) nerow[d] = ne_t[(long)n * D_ + d];

    float acc[4][4];
#pragma unroll
    for (int j = 0; j < 4; j++) {
        int o = ob + tc * 4 + j;
        float bv = 0.f;
#pragma unroll
        for (int d = 0; d < D_; d++) bv = fmaf(nerow[d], bpool[(long)d * outdim + o], bv);
#pragma unroll
        for (int i = 0; i < 4; i++) acc[i][j] = bv;
    }

    for (int k = 0; k < K_; k++) {
        for (int ib = 0; ib < cin; ib += 16) {
            // stage xg tile (transposed) with zero-pad past cin
#pragma unroll
            for (int p = 0; p < 4; p++) {
                int idx = tid + p * 256;
                int ii = idx & 15, bl = idx >> 4;
                int gi = ib + ii;
                xs[ii][bl] = (gi < cin) ? xg[(((long)k * N_ + n) * B_ + bl) * cin + gi] : 0.f;
            }
            // generate pooled weight tile from Wr (d contiguous)
#pragma unroll
            for (int p = 0; p < 4; p++) {
                int ii = iq * 4 + p;
                int gi = ib + ii;
                float w = 0.f;
                if (gi < cin) {
                    const float* wp = Wr + (((long)k * cin + gi) * outdim + ob + ol) * D_;
#pragma unroll
                    for (int d = 0; d < D_; d += 4) {
                        float4 wv = *(const float4*)&wp[d];
                        w = fmaf(nerow[d + 0], wv.x, w);
                        w = fmaf(nerow[d + 1], wv.y, w);
                        w = fmaf(nerow[d + 2], wv.z, w);
                        w = fmaf(nerow[d + 3], wv.w, w);
                    }
                }
                wsd[ii][ol] = w;
            }
            __syncthreads();
#pragma unroll
            for (int kk = 0; kk < 16; kk++) {
                float a[4], b4[4];
                *(float4*)&a[0]  = *(const float4*)&xs[kk][tr * 4];
                *(float4*)&b4[0] = *(const float4*)&wsd[kk][tc * 4];
#pragma unroll
                for (int i = 0; i < 4; i++)
#pragma unroll
                    for (int j = 0; j < 4; j++) acc[i][j] = fmaf(a[i], b4[j], acc[i][j]);
            }
            __syncthreads();
        }
    }

    if (mode == 1) {
#pragma unroll
        for (int i = 0; i < 4; i++) {
            int b = tr * 4 + i;
#pragma unroll
            for (int j = 0; j < 4; j++) {
                int o = ob + tc * 4 + j;
                float v = 1.f / (1.f + __expf(-acc[i][j]));
                dst[(long)n * dn + (long)b * db + o] = v;
            }
        }
    } else {
#pragma unroll
        for (int i = 0; i < 4; i++) {
            int b = tr * 4 + i;
#pragma unroll
            for (int j = 0; j < 4; j++) {
                int o = ob + tc * 4 + j;
                float hc = tanhf(acc[i][j]);
                float r = zr[((long)n * B_ + b) * (2 * H_) + H_ + o];
                long hidx = ((long)n * B_ + b) * H_ + o;
                float hn = r * h[hidx] + (1.f - r) * hc;
                h[hidx] = hn;
                dst[(long)n * dn + (long)b * db + o] = hn;
            }
        }
    }
}

// ---------------------------------------------------------------------------
extern "C" void kernel_launch(void* const* d_in, const int* in_sizes, int n_in,
                              void* d_out, int out_size, void* d_ws, size_t ws_size,
                              hipStream_t stream) {
    const float* source   = (const float*)d_in[0];
    const float* node_emb = (const float*)d_in[1];
    const float* time_emb = (const float*)d_in[2];
    float* out = (float*)d_out;
    float* ws  = (float*)d_ws;

    const long NN = (long)N_ * N_;
    float* ne_g = ws;
    float* ne_u = ne_g + (long)T_ * N_ * D_;
    float* S_g  = ne_u + (long)T_ * N_ * D_;
    float* S_u  = S_g + T_ * NN;
    float* xg   = S_u + T_ * NN;                    // 3 * N * B * 256 (max cin)
    float* zr   = xg + 3L * N_ * B_ * 256;
    float* h    = zr + (long)N_ * B_ * 256;
    float* cur0 = h + (long)N_ * B_ * H_;
    float* Wr_g = cur0 + (long)T_ * N_ * B_ * H_;   // K*256*256*D max
    float* Wr_u = Wr_g + 3L * 256 * 256 * D_;
    float* wend = Wr_u + 3L * 256 * 128 * D_;
    if ((size_t)(wend - ws) * sizeof(float) > ws_size) return;  // ws guard

    for (int layer = 0; layer < 2; ++layer) {
        const float* gW   = (const float*)d_in[3 + layer * 8 + 0];
        const float* gb   = (const float*)d_in[3 + layer * 8 + 1];
        const float* glng = (const float*)d_in[3 + layer * 8 + 2];
        const float* glnb = (const float*)d_in[3 + layer * 8 + 3];
        const float* uW   = (const float*)d_in[3 + layer * 8 + 4];
        const float* ub   = (const float*)d_in[3 + layer * 8 + 5];
        const float* ulng = (const float*)d_in[3 + layer * 8 + 6];
        const float* ulnb = (const float*)d_in[3 + layer * 8 + 7];
        const int cin = (layer == 0) ? (DIN_ + H_) : (2 * H_);
        const int cx  = (layer == 0) ? DIN_ : H_;
        const int F   = B_ * cin;

        ln_kernel<<<dim3((T_ * N_ + 255) / 256), dim3(256), 0, stream>>>(node_emb, time_emb, glng, glnb, ne_g);
        ln_kernel<<<dim3((T_ * N_ + 255) / 256), dim3(256), 0, stream>>>(node_emb, time_emb, ulng, ulnb, ne_u);
        support_softmax<<<dim3(T_ * N_), dim3(64), 0, stream>>>(ne_g, S_g);
        support_softmax<<<dim3(T_ * N_), dim3(64), 0, stream>>>(ne_u, S_u);
        {
            int tg = K_ * cin * (2 * H_) * D_;
            int tu = K_ * cin * H_ * D_;
            reorder_W<<<dim3((tg + 255) / 256), dim3(256), 0, stream>>>(gW, Wr_g, cin, 2 * H_);
            reorder_W<<<dim3((tu + 255) / 256), dim3(256), 0, stream>>>(uW, Wr_u, cin, H_);
        }
        hipMemsetAsync(h, 0, (size_t)N_ * B_ * H_ * sizeof(float), stream);

        for (int t = 0; t < T_; ++t) {
            const float* xt; long sb, sn;
            if (layer == 0) { xt = source + (long)t * N_ * DIN_; sb = (long)T_ * N_ * DIN_; sn = DIN_; }
            else            { xt = cur0 + (long)t * N_ * B_ * H_; sb = H_; sn = (long)B_ * H_; }

            // ---- gate (z, r) ----
            build_xcat<<<dim3((F + 255) / 256, N_), dim3(256), 0, stream>>>(xg, xt, sb, sn, cx, cin, h, nullptr, 0);
            gemm128<<<dim3(F / 128, N_ / 128), dim3(256), 0, stream>>>(S_g + t * NN, xg, xg + (long)N_ * F, N_, F, 1.f, nullptr);
            gemm128<<<dim3(F / 128, N_ / 128), dim3(256), 0, stream>>>(S_g + t * NN, xg + (long)N_ * F, xg + 2L * N_ * F, N_, F, 2.f, xg);
            node_gemm<<<dim3((2 * H_) / 64, N_), dim3(256), 0, stream>>>(
                xg, ne_g + (long)t * N_ * D_, Wr_g, gb, cin, 2 * H_, 1,
                nullptr, nullptr, zr, (long)B_ * 2 * H_, (long)2 * H_);

            // ---- candidate + h update ----
            build_xcat<<<dim3((F + 255) / 256, N_), dim3(256), 0, stream>>>(xg, xt, sb, sn, cx, cin, h, zr, 1);
            gemm128<<<dim3(F / 128, N_ / 128), dim3(256), 0, stream>>>(S_u + t * NN, xg, xg + (long)N_ * F, N_, F, 1.f, nullptr);
            gemm128<<<dim3(F / 128, N_ / 128), dim3(256), 0, stream>>>(S_u + t * NN, xg + (long)N_ * F, xg + 2L * N_ * F, N_, F, 2.f, xg);
            float* dst; long dn, db;
            if (layer == 0) { dst = cur0 + (long)t * N_ * B_ * H_; dn = (long)B_ * H_; db = H_; }
            else            { dst = out + (long)t * N_ * H_; dn = H_; db = (long)T_ * N_ * H_; }
            node_gemm<<<dim3(H_ / 64, N_), dim3(256), 0, stream>>>(
                xg, ne_u + (long)t * N_ * D_, Wr_u, ub, cin, H_, 2,
                zr, h, dst, dn, db);
        }
    }
}

// Round 3
// 14586.617 us; speedup vs baseline: 1.4871x; 1.4871x over previous
//
#include <hip/hip_runtime.h>

// AGGCN: split-precision bf16 MFMA (hi+lo, 3-pass) version.
// N=512, T=12, B=64, DIN=2, H=128, D=16, K=3, 2 layers.
// cin padded: layer0 130->160, layer1 256->256.

constexpr int N_ = 512, T_ = 12, B_ = 64, DIN_ = 2, H_ = 128, D_ = 16, K_ = 3;

typedef __attribute__((ext_vector_type(8))) short short8;
typedef __attribute__((ext_vector_type(4))) float floatx4;

__device__ __forceinline__ unsigned short f2bf(float f) {
    unsigned int u = __builtin_bit_cast(unsigned int, f);
    u += 0x7fffu + ((u >> 16) & 1u);
    return (unsigned short)(u >> 16);
}
__device__ __forceinline__ float bf2f(unsigned short h) {
    unsigned int u = ((unsigned int)h) << 16;
    return __builtin_bit_cast(float, u);
}
// split v ~= hi + lo (each bf16); lo captures the hi-rounding residual.
__device__ __forceinline__ void splitbf(float v, unsigned short& hh, unsigned short& ll) {
    hh = f2bf(v);
    ll = f2bf(v - bf2f(hh));
}

// ---------------------------------------------------------------------------
// LayerNorm over D=16 of (node_emb[n] + time_emb[t]) -> ne fp32
__global__ void ln_kernel(const float* __restrict__ nemb, const float* __restrict__ temb,
                          const float* __restrict__ g, const float* __restrict__ b,
                          float* __restrict__ ne) {
    int idx = blockIdx.x * 256 + threadIdx.x;
    if (idx >= T_ * N_) return;
    int t = idx / N_, n = idx % N_;
    float x[D_];
    float m = 0.f;
#pragma unroll
    for (int d = 0; d < D_; d++) { x[d] = nemb[n * D_ + d] + temb[t * D_ + d]; m += x[d]; }
    m *= (1.f / D_);
    float v = 0.f;
#pragma unroll
    for (int d = 0; d < D_; d++) { float c = x[d] - m; v += c * c; }
    v *= (1.f / D_);
    float rs = rsqrtf(v + 1e-12f);
#pragma unroll
    for (int d = 0; d < D_; d++) ne[(long)idx * D_ + d] = (x[d] - m) * rs * g[d] + b[d];
}

// ---------------------------------------------------------------------------
// S[t] = row-softmax(ne[t] @ ne[t]^T) -> bf16 hi/lo planes, row-major [dst][src]
__global__ void support_softmax(const float* __restrict__ ne,
                                unsigned short* __restrict__ Sh, unsigned short* __restrict__ Sl) {
    int rid = blockIdx.x;            // t*N + n
    int t = rid / N_, n = rid % N_;
    const float* net = ne + (long)t * N_ * D_;
    int lane = threadIdx.x;          // 64
    float r[D_];
#pragma unroll
    for (int d = 0; d < D_; d++) r[d] = net[(long)n * D_ + d];
    float v[8];
    float mx = -1e30f;
#pragma unroll
    for (int jj = 0; jj < 8; jj++) {
        const float* nj = net + (long)(jj * 64 + lane) * D_;
        float acc = 0.f;
#pragma unroll
        for (int d = 0; d < D_; d++) acc = fmaf(r[d], nj[d], acc);
        v[jj] = acc;
        mx = fmaxf(mx, acc);
    }
#pragma unroll
    for (int off = 32; off >= 1; off >>= 1) mx = fmaxf(mx, __shfl_xor(mx, off, 64));
    float s = 0.f;
#pragma unroll
    for (int jj = 0; jj < 8; jj++) { v[jj] = __expf(v[jj] - mx); s += v[jj]; }
#pragma unroll
    for (int off = 32; off >= 1; off >>= 1) s += __shfl_xor(s, off, 64);
    float inv = 1.f / s;
#pragma unroll
    for (int jj = 0; jj < 8; jj++) {
        unsigned short hh, ll;
        splitbf(v[jj] * inv, hh, ll);
        Sh[(long)rid * N_ + jj * 64 + lane] = hh;
        Sl[(long)rid * N_ + jj * 64 + lane] = ll;
    }
}

// ---------------------------------------------------------------------------
// W (D,K,cin,out) fp32 -> Wr (K,cinp,out,D) fp32, zero for i>=cin.
__global__ void reorder_W(const float* __restrict__ W, float* __restrict__ Wr,
                          int cin, int cinp, int outdim) {
    int total = K_ * cinp * outdim * D_;
    int idx = blockIdx.x * 256 + threadIdx.x;
    if (idx >= total) return;
    int d = idx & (D_ - 1);
    int rest = idx >> 4;            // (k*cinp + i)*outdim + o
    int o = rest % outdim;
    int ki = rest / outdim;
    int i = ki % cinp, kk = ki / cinp;
    float val = 0.f;
    if (i < cin) val = W[(((long)d * K_ + kk) * cin + i) * outdim + o];
    Wr[idx] = val;
}

// ---------------------------------------------------------------------------
// x0 = concat(xt, (z*)h), split bf16, dual layout:
//  xgN[n][b*cinp+c] (node-major) hi/lo;  xgA[(b*cinp+c)][n] (F-major) hi/lo.
__global__ void build_xcat(unsigned short* __restrict__ xgAh, unsigned short* __restrict__ xgAl,
                           unsigned short* __restrict__ xgNh, unsigned short* __restrict__ xgNl,
                           const void* __restrict__ xt, int xt_i16, long sb, long sn,
                           int cx, int cin, int cinp,
                           const float* __restrict__ h, const float* __restrict__ zr) {
    int n = blockIdx.y;
    int idx = blockIdx.x * 256 + threadIdx.x;   // b*cinp + c (grid exact)
    int b = idx / cinp, c = idx - b * cinp;
    float v = 0.f;
    if (c < cx) {
        v = xt_i16 ? (float)((const short*)xt)[(long)b * sb + (long)n * sn + c] * (1.f / 32767.f)
                   : ((const float*)xt)[(long)b * sb + (long)n * sn + c];
    } else if (c < cin) {
        int q = c - cx;
        v = h[((long)n * B_ + b) * H_ + q];
        if (zr) v *= zr[((long)n * B_ + b) * (2 * H_) + q];
    }
    unsigned short hh, ll;
    splitbf(v, hh, ll);
    xgNh[(long)n * B_ * cinp + idx] = hh;
    xgNl[(long)n * B_ * cinp + idx] = ll;
    xgAh[(long)idx * N_ + n] = hh;
    xgAl[(long)idx * N_ + n] = ll;
}

// ---------------------------------------------------------------------------
// Graph prop, split bf16 3-pass MFMA: out[f,dst] = sum_src X[f,src]*S[dst,src]
// 128x128 tile, BK=32, 4 waves of 64x64 each.
// outN hi/lo: [dst][f]. outA hi/lo: [f][dst] (P1 only).
// subN hi/lo: Chebyshev  val = 2*acc - x0  (P2 only).
__global__ __launch_bounds__(256) void prop_mfma(
    const unsigned short* __restrict__ XAh, const unsigned short* __restrict__ XAl,
    const unsigned short* __restrict__ Sh,  const unsigned short* __restrict__ Sl,
    unsigned short* __restrict__ outAh, unsigned short* __restrict__ outAl,
    unsigned short* __restrict__ outNh, unsigned short* __restrict__ outNl,
    const unsigned short* __restrict__ subNh, const unsigned short* __restrict__ subNl,
    int Fp) {
    __shared__ short Ash[128 * 40];
    __shared__ short Asl[128 * 40];
    __shared__ short Ssh[128 * 40];
    __shared__ short Ssl[128 * 40];
    int tid = threadIdx.x;
    int bm = blockIdx.x * 128, bn = blockIdx.y * 128;
    int w = tid >> 6, lane15 = tid & 15, quad = (tid >> 4) & 3;
    int mw = (w & 1) * 64, nw = (w >> 1) * 64;
    floatx4 acc[4][4];
#pragma unroll
    for (int mt = 0; mt < 4; mt++)
#pragma unroll
        for (int nt = 0; nt < 4; nt++) acc[mt][nt] = (floatx4){0.f, 0.f, 0.f, 0.f};

    for (int s0 = 0; s0 < N_; s0 += 32) {
#pragma unroll
        for (int p = 0; p < 2; p++) {
            int c = tid + p * 256;
            int row = c >> 2, col = (c & 3) * 8;
            *(short8*)&Ash[row * 40 + col] = *(const short8*)(XAh + (long)(bm + row) * N_ + s0 + col);
            *(short8*)&Asl[row * 40 + col] = *(const short8*)(XAl + (long)(bm + row) * N_ + s0 + col);
            *(short8*)&Ssh[row * 40 + col] = *(const short8*)(Sh + (long)(bn + row) * N_ + s0 + col);
            *(short8*)&Ssl[row * 40 + col] = *(const short8*)(Sl + (long)(bn + row) * N_ + s0 + col);
        }
        __syncthreads();
        short8 ah[4], al[4];
#pragma unroll
        for (int mt = 0; mt < 4; mt++) {
            ah[mt] = *(const short8*)&Ash[(mw + mt * 16 + lane15) * 40 + quad * 8];
            al[mt] = *(const short8*)&Asl[(mw + mt * 16 + lane15) * 40 + quad * 8];
        }
#pragma unroll
        for (int nt = 0; nt < 4; nt++) {
            short8 bh = *(const short8*)&Ssh[(nw + nt * 16 + lane15) * 40 + quad * 8];
            short8 bl = *(const short8*)&Ssl[(nw + nt * 16 + lane15) * 40 + quad * 8];
#pragma unroll
            for (int mt = 0; mt < 4; mt++) {
                acc[mt][nt] = __builtin_amdgcn_mfma_f32_16x16x32_bf16(ah[mt], bh, acc[mt][nt], 0, 0, 0);
                acc[mt][nt] = __builtin_amdgcn_mfma_f32_16x16x32_bf16(al[mt], bh, acc[mt][nt], 0, 0, 0);
                acc[mt][nt] = __builtin_amdgcn_mfma_f32_16x16x32_bf16(ah[mt], bl, acc[mt][nt], 0, 0, 0);
            }
        }
        __syncthreads();
    }

#pragma unroll
    for (int mt = 0; mt < 4; mt++) {
        int f0 = bm + mw + mt * 16 + quad * 4;
#pragma unroll
        for (int nt = 0; nt < 4; nt++) {
            int dst = bn + nw + nt * 16 + lane15;
            float v[4] = {acc[mt][nt][0], acc[mt][nt][1], acc[mt][nt][2], acc[mt][nt][3]};
            if (subNh) {
                ushort4 sh4 = *(const ushort4*)(subNh + (long)dst * Fp + f0);
                ushort4 sl4 = *(const ushort4*)(subNl + (long)dst * Fp + f0);
                v[0] = 2.f * v[0] - (bf2f(sh4.x) + bf2f(sl4.x));
                v[1] = 2.f * v[1] - (bf2f(sh4.y) + bf2f(sl4.y));
                v[2] = 2.f * v[2] - (bf2f(sh4.z) + bf2f(sl4.z));
                v[3] = 2.f * v[3] - (bf2f(sh4.w) + bf2f(sl4.w));
            }
            ushort4 oh, ol;
            splitbf(v[0], oh.x, ol.x); splitbf(v[1], oh.y, ol.y);
            splitbf(v[2], oh.z, ol.z); splitbf(v[3], oh.w, ol.w);
            *(ushort4*)(outNh + (long)dst * Fp + f0) = oh;
            *(ushort4*)(outNl + (long)dst * Fp + f0) = ol;
            if (outAh) {
                unsigned short* pah = outAh + (long)f0 * N_ + dst;
                unsigned short* pal = outAl + (long)f0 * N_ + dst;
                pah[0] = oh.x; pah[N_] = oh.y; pah[2 * N_] = oh.z; pah[3 * N_] = oh.w;
                pal[0] = ol.x; pal[N_] = ol.y; pal[2 * N_] = ol.z; pal[3 * N_] = ol.w;
            }
        }
    }
}

// ---------------------------------------------------------------------------
// Fused node GEMM, split precision. Block = 4 nodes (1/wave) x 64 o-cols.
// Pool Wp[i][o] = sum_d ne[n,d]*Wr[k,i,o,d] in fp32 (once per element),
// split into LDS hi/lo; 3-pass 16x16x32 bf16 MFMA vs xgN hi/lo.
// grid.x = node-block (fast) so co-resident blocks share the Wr o-strip in L2.
// mode 1: sigmoid -> zrOut(dstF). mode 2: tanh, h'=r*h+(1-r)*hc -> h + dstF|dstI.
__global__ __launch_bounds__(256) void node_mfma(
    const unsigned short* __restrict__ xgNh, const unsigned short* __restrict__ xgNl,
    const float* __restrict__ ne_t,
    const float* __restrict__ Wr, const float* __restrict__ bpool,
    int cinp, int outdim, int mode,
    const float* __restrict__ zrIn, float* __restrict__ h,
    float* __restrict__ dstF, short* __restrict__ dstI,
    long dn, long db) {
    __shared__ short Wph[4 * 64 * 40];
    __shared__ short Wpl[4 * 64 * 40];
    int tid = threadIdx.x;
    int n0 = blockIdx.x * 4;
    int ob = blockIdx.y * 64;
    int w = tid >> 6, lane15 = tid & 15, quad = (tid >> 4) & 3;
    int oo = tid & 63;
    int Fp = B_ * cinp;
    int myn = n0 + w;

    float ner[4][16];
#pragma unroll
    for (int g = 0; g < 4; g++)
#pragma unroll
        for (int d = 0; d < D_; d++) ner[g][d] = ne_t[(long)(n0 + g) * D_ + d];

    float bias[4];
#pragma unroll
    for (int nt = 0; nt < 4; nt++) {
        int o = ob + nt * 16 + lane15;
        float bv = 0.f;
#pragma unroll
        for (int d = 0; d < D_; d++) bv = fmaf(ner[w][d], bpool[(long)d * outdim + o], bv);
        bias[nt] = bv;
    }
    floatx4 acc[4][4];
#pragma unroll
    for (int mt = 0; mt < 4; mt++)
#pragma unroll
        for (int nt = 0; nt < 4; nt++) acc[mt][nt] = (floatx4){bias[nt], bias[nt], bias[nt], bias[nt]};

    for (int kk = 0; kk < K_; kk++) {
        const unsigned short* xbh = xgNh + ((long)kk * N_ + myn) * Fp;
        const unsigned short* xbl = xgNl + ((long)kk * N_ + myn) * Fp;
        for (int i0 = 0; i0 < cinp; i0 += 32) {
            // ---- fp32 pooling: thread covers o=oo, i = i0 + w*8 + il, all 4 nodes ----
            float pool[4][8];
#pragma unroll
            for (int g = 0; g < 4; g++)
#pragma unroll
                for (int il = 0; il < 8; il++) pool[g][il] = 0.f;
#pragma unroll
            for (int il = 0; il < 8; il++) {
                const float* wp = Wr + ((long)(kk * cinp + i0 + w * 8 + il) * outdim + ob + oo) * D_;
                float4 w0 = *(const float4*)(wp + 0);
                float4 w1 = *(const float4*)(wp + 4);
                float4 w2 = *(const float4*)(wp + 8);
                float4 w3 = *(const float4*)(wp + 12);
                float wv[16] = {w0.x, w0.y, w0.z, w0.w, w1.x, w1.y, w1.z, w1.w,
                                w2.x, w2.y, w2.z, w2.w, w3.x, w3.y, w3.z, w3.w};
#pragma unroll
                for (int d = 0; d < D_; d++)
#pragma unroll
                    for (int g = 0; g < 4; g++) pool[g][il] = fmaf(ner[g][d], wv[d], pool[g][il]);
            }
            __syncthreads();   // previous slab's frag reads complete
#pragma unroll
            for (int g = 0; g < 4; g++) {
                short8 vh, vl;
#pragma unroll
                for (int il = 0; il < 8; il++) {
                    unsigned short hh, ll;
                    splitbf(pool[g][il], hh, ll);
                    vh[il] = (short)hh; vl[il] = (short)ll;
                }
                *(short8*)&Wph[(g * 64 + oo) * 40 + w * 8] = vh;
                *(short8*)&Wpl[(g * 64 + oo) * 40 + w * 8] = vl;
            }
            __syncthreads();
            // ---- 3-pass MFMA ----
            short8 ah[4], al[4];
#pragma unroll
            for (int mt = 0; mt < 4; mt++) {
                ah[mt] = *(const short8*)(xbh + (long)(mt * 16 + lane15) * cinp + i0 + quad * 8);
                al[mt] = *(const short8*)(xbl + (long)(mt * 16 + lane15) * cinp + i0 + quad * 8);
            }
#pragma unroll
            for (int nt = 0; nt < 4; nt++) {
                short8 bh = *(const short8*)&Wph[(w * 64 + nt * 16 + lane15) * 40 + quad * 8];
                short8 bl = *(const short8*)&Wpl[(w * 64 + nt * 16 + lane15) * 40 + quad * 8];
#pragma unroll
                for (int mt = 0; mt < 4; mt++) {
                    acc[mt][nt] = __builtin_amdgcn_mfma_f32_16x16x32_bf16(ah[mt], bh, acc[mt][nt], 0, 0, 0);
                    acc[mt][nt] = __builtin_amdgcn_mfma_f32_16x16x32_bf16(al[mt], bh, acc[mt][nt], 0, 0, 0);
                    acc[mt][nt] = __builtin_amdgcn_mfma_f32_16x16x32_bf16(ah[mt], bl, acc[mt][nt], 0, 0, 0);
                }
            }
        }
    }

#pragma unroll
    for (int mt = 0; mt < 4; mt++) {
        int b0 = mt * 16 + quad * 4;
#pragma unroll
        for (int nt = 0; nt < 4; nt++) {
            int o = ob + nt * 16 + lane15;
#pragma unroll
            for (int r = 0; r < 4; r++) {
                float v = acc[mt][nt][r];
                int bb = b0 + r;
                if (mode == 1) {
                    float s = 1.f / (1.f + __expf(-v));
                    dstF[(long)myn * dn + (long)bb * db + o] = s;
                } else {
                    float hc = tanhf(v);
                    long bi = (long)myn * B_ + bb;
                    float rr = zrIn[bi * (2 * H_) + H_ + o];
                    float hn = rr * h[bi * H_ + o] + (1.f - rr) * hc;
                    h[bi * H_ + o] = hn;
                    if (dstF) dstF[(long)myn * dn + (long)bb * db + o] = hn;
                    else {
                        int q = __float2int_rn(hn * 32767.f);
                        q = q > 32767 ? 32767 : (q < -32767 ? -32767 : q);
                        dstI[(long)myn * dn + (long)bb * db + o] = (short)q;
                    }
                }
            }
        }
    }
}

// ---------------------------------------------------------------------------
extern "C" void kernel_launch(void* const* d_in, const int* in_sizes, int n_in,
                              void* d_out, int out_size, void* d_ws, size_t ws_size,
                              hipStream_t stream) {
    const float* source   = (const float*)d_in[0];
    const float* node_emb = (const float*)d_in[1];
    const float* time_emb = (const float*)d_in[2];
    float* out = (float*)d_out;

    char* p = (char*)d_ws;
    auto carve = [&](size_t bytes) { char* r = p; p += (bytes + 255) & ~255ull; return r; };
    float*          ne_g  = (float*)carve((size_t)T_ * N_ * D_ * 4);
    float*          ne_u  = (float*)carve((size_t)T_ * N_ * D_ * 4);
    unsigned short* S_gh  = (unsigned short*)carve((size_t)T_ * N_ * N_ * 2);
    unsigned short* S_gl  = (unsigned short*)carve((size_t)T_ * N_ * N_ * 2);
    unsigned short* S_uh  = (unsigned short*)carve((size_t)T_ * N_ * N_ * 2);
    unsigned short* S_ul  = (unsigned short*)carve((size_t)T_ * N_ * N_ * 2);
    float*          Wr_g  = (float*)carve((size_t)K_ * 256 * 256 * D_ * 4);
    float*          Wr_u  = (float*)carve((size_t)K_ * 256 * 128 * D_ * 4);
    unsigned short* xgA0h = (unsigned short*)carve((size_t)64 * 256 * N_ * 2);
    unsigned short* xgA0l = (unsigned short*)carve((size_t)64 * 256 * N_ * 2);
    unsigned short* xgA1h = (unsigned short*)carve((size_t)64 * 256 * N_ * 2);
    unsigned short* xgA1l = (unsigned short*)carve((size_t)64 * 256 * N_ * 2);
    unsigned short* xgNh  = (unsigned short*)carve((size_t)K_ * N_ * 64 * 256 * 2);
    unsigned short* xgNl  = (unsigned short*)carve((size_t)K_ * N_ * 64 * 256 * 2);
    float*          zr    = (float*)carve((size_t)N_ * B_ * 2 * H_ * 4);
    float*          h     = (float*)carve((size_t)N_ * B_ * H_ * 4);
    short*          cur0  = (short*)carve((size_t)T_ * N_ * B_ * H_ * 2);
    if ((size_t)(p - (char*)d_ws) > ws_size) return;  // ws guard (~364 MB)

    for (int layer = 0; layer < 2; ++layer) {
        const float* gW   = (const float*)d_in[3 + layer * 8 + 0];
        const float* gb   = (const float*)d_in[3 + layer * 8 + 1];
        const float* glng = (const float*)d_in[3 + layer * 8 + 2];
        const float* glnb = (const float*)d_in[3 + layer * 8 + 3];
        const float* uW   = (const float*)d_in[3 + layer * 8 + 4];
        const float* ub   = (const float*)d_in[3 + layer * 8 + 5];
        const float* ulng = (const float*)d_in[3 + layer * 8 + 6];
        const float* ulnb = (const float*)d_in[3 + layer * 8 + 7];
        const int cin  = (layer == 0) ? (DIN_ + H_) : (2 * H_);
        const int cinp = (layer == 0) ? 160 : 256;
        const int cx   = (layer == 0) ? DIN_ : H_;
        const int Fp   = B_ * cinp;
        const long sliceN = (long)N_ * Fp;

        ln_kernel<<<dim3(24), dim3(256), 0, stream>>>(node_emb, time_emb, glng, glnb, ne_g);
        ln_kernel<<<dim3(24), dim3(256), 0, stream>>>(node_emb, time_emb, ulng, ulnb, ne_u);
        support_softmax<<<dim3(T_ * N_), dim3(64), 0, stream>>>(ne_g, S_gh, S_gl);
        support_softmax<<<dim3(T_ * N_), dim3(64), 0, stream>>>(ne_u, S_uh, S_ul);
        reorder_W<<<dim3(K_ * cinp * (2 * H_) * D_ / 256), dim3(256), 0, stream>>>(gW, Wr_g, cin, cinp, 2 * H_);
        reorder_W<<<dim3(K_ * cinp * H_ * D_ / 256), dim3(256), 0, stream>>>(uW, Wr_u, cin, cinp, H_);
        hipMemsetAsync(h, 0, (size_t)N_ * B_ * H_ * sizeof(float), stream);

        for (int t = 0; t < T_; ++t) {
            const void* xt; long sb, sn; int xi16;
            if (layer == 0) { xt = source + (long)t * N_ * DIN_; sb = (long)T_ * N_ * DIN_; sn = DIN_; xi16 = 0; }
            else            { xt = cur0 + (long)t * N_ * B_ * H_; sb = H_; sn = (long)B_ * H_; xi16 = 1; }
            const unsigned short* Sgh = S_gh + (long)t * N_ * N_;
            const unsigned short* Sgl = S_gl + (long)t * N_ * N_;
            const unsigned short* Suh = S_uh + (long)t * N_ * N_;
            const unsigned short* Sul = S_ul + (long)t * N_ * N_;

            // ---- gate (z, r) ----
            build_xcat<<<dim3(B_ * cinp / 256, N_), dim3(256), 0, stream>>>(
                xgA0h, xgA0l, xgNh, xgNl, xt, xi16, sb, sn, cx, cin, cinp, h, nullptr);
            prop_mfma<<<dim3(Fp / 128, 4), dim3(256), 0, stream>>>(
                xgA0h, xgA0l, Sgh, Sgl, xgA1h, xgA1l,
                xgNh + sliceN, xgNl + sliceN, nullptr, nullptr, Fp);
            prop_mfma<<<dim3(Fp / 128, 4), dim3(256), 0, stream>>>(
                xgA1h, xgA1l, Sgh, Sgl, nullptr, nullptr,
                xgNh + 2 * sliceN, xgNl + 2 * sliceN, xgNh, xgNl, Fp);
            node_mfma<<<dim3(N_ / 4, 2 * H_ / 64), dim3(256), 0, stream>>>(
                xgNh, xgNl, ne_g + (long)t * N_ * D_, Wr_g, gb, cinp, 2 * H_, 1,
                nullptr, nullptr, zr, nullptr, (long)B_ * 2 * H_, (long)2 * H_);

            // ---- candidate + h update ----
            build_xcat<<<dim3(B_ * cinp / 256, N_), dim3(256), 0, stream>>>(
                xgA0h, xgA0l, xgNh, xgNl, xt, xi16, sb, sn, cx, cin, cinp, h, zr);
            prop_mfma<<<dim3(Fp / 128, 4), dim3(256), 0, stream>>>(
                xgA0h, xgA0l, Suh, Sul, xgA1h, xgA1l,
                xgNh + sliceN, xgNl + sliceN, nullptr, nullptr, Fp);
            prop_mfma<<<dim3(Fp / 128, 4), dim3(256), 0, stream>>>(
                xgA1h, xgA1l, Suh, Sul, nullptr, nullptr,
                xgNh + 2 * sliceN, xgNl + 2 * sliceN, xgNh, xgNl, Fp);
            float* dstF; short* dstI; long dn, db;
            if (layer == 0) { dstF = nullptr; dstI = cur0 + (long)t * N_ * B_ * H_; dn = (long)B_ * H_; db = H_; }
            else            { dstF = out + (long)t * N_ * H_; dstI = nullptr; dn = H_; db = (long)T_ * N_ * H_; }
            node_mfma<<<dim3(N_ / 4, H_ / 64), dim3(256), 0, stream>>>(
                xgNh, xgNl, ne_u + (long)t * N_ * D_, Wr_u, ub, cinp, H_, 2,
                zr, h, dstF, dstI, dn, db);
        }
    }
}